// Round 1
// baseline (114.250 us; speedup 1.0000x reference)
//
#include <hip/hip_runtime.h>

// VQ: z [32,256,32,32] f32, codebook [1024,256] f32
// out: z_q [32,256,32,32] f32 (8388608) then loss scalar f32 (1)
#define NELEM 8388608

typedef __attribute__((ext_vector_type(4))) float f32x4;
typedef unsigned long long ull;

// ---------------------------------------------------------------------------
// prep: codebook -> fp8 e4m3 (scaled x256, exact pow2) in B-fragment-linear
// order for mfma_f32_16x16x32_fp8_fp8, plus exact fp32 norms cn[k].
// frag g = nt*8+ks (512 B): lane L holds cb[nt*16+(L&15)][ks*32+(L>>4)*8+0..7]
// Also zeroes the loss scalar (replaces the separate hipMemsetAsync dispatch).
__global__ __launch_bounds__(256) void prep_kernel(const float* __restrict__ cb,
                                                   uint2* __restrict__ cbf8,
                                                   float* __restrict__ cn,
                                                   float* __restrict__ loss) {
    if (blockIdx.x == 0 && threadIdx.x == 0) *loss = 0.f;

    const int t = threadIdx.x;
    const int gt = blockIdx.x * 256 + t;          // 0..32767
    const int L = gt & 63, g = gt >> 6;           // frag 0..511
    const int nt = g >> 3, ks = g & 7;
    const int code = nt * 16 + (L & 15);
    const int k0 = ks * 32 + (L >> 4) * 8;
    const float* s = cb + code * 256 + k0;
    float v[8];
    #pragma unroll
    for (int j = 0; j < 8; ++j) v[j] = s[j] * 256.0f;
    int lo = 0, hi = 0;
    lo = __builtin_amdgcn_cvt_pk_fp8_f32(v[0], v[1], lo, false);
    lo = __builtin_amdgcn_cvt_pk_fp8_f32(v[2], v[3], lo, true);
    hi = __builtin_amdgcn_cvt_pk_fp8_f32(v[4], v[5], hi, false);
    hi = __builtin_amdgcn_cvt_pk_fp8_f32(v[6], v[7], hi, true);
    uint2 o; o.x = (unsigned)lo; o.y = (unsigned)hi;
    cbf8[g * 64 + L] = o;

    const int w = t >> 6, lane = t & 63;
    #pragma unroll
    for (int cc = 0; cc < 2; ++cc) {
        int cd = blockIdx.x * 8 + w * 2 + cc;
        float4 qv = *(const float4*)(cb + cd * 256 + lane * 4);
        float s2 = qv.x*qv.x + qv.y*qv.y + qv.z*qv.z + qv.w*qv.w;
        #pragma unroll
        for (int off = 32; off; off >>= 1) s2 += __shfl_down(s2, off, 64);
        if (lane == 0) cn[cd] = s2;
    }
}

// ---------------------------------------------------------------------------
// Fused argmin + gather + transpose-store + loss.
// Grid 512 blocks x 256 thr, 2 blocks/CU. Block = 64 pos x 1024 codes.
// NEW decomposition: per iteration (64 codes), wave w owns nt-group it*4+w
// (16 codes) against ALL 64 positions -> B-chunk is read from LDS exactly
// once per block per iter (8 ds_read_b64/wave) instead of 4x (32/wave).
// A-frags (all 4 m-frags) are exchanged once through LDS and then live in
// 64 VGPRs for the whole loop. dist = cn - 2*dot; nt packed into 6 low
// mantissa bits. loss = 1.25/NELEM * sum(z^2_exact + dmin).
__global__ __launch_bounds__(256, 2) void vq_kernel(
        const float* __restrict__ z, const uint4* __restrict__ cbf8,
        const float* __restrict__ cb, const float* __restrict__ cn,
        float* __restrict__ out, float* __restrict__ loss) {
    __shared__ union {
        struct {
            float cn[1024];          // 4 KB
            uint4 B[2][1024];        // 32 KB double-buffered fp8 chunks
            ull   A[4][8][64];       // 16 KB one-time A-frag exchange
        } p1;                        // 52 KB
        float Q[32][257];            // 32.9 KB (epilogue transpose)
    } S;
    __shared__ int   codeS[64];
    __shared__ float Dw[4][64];
    __shared__ int   Cw[4][64];
    __shared__ float wsum[4];

    const int t = threadIdx.x, w = t >> 6, L = t & 63;
    const int col = L & 15, q = L >> 4;
    const int blk = blockIdx.x;
    const int b = blk >> 4, hw0 = (blk & 15) << 6;

    // stage cn (per-iter epilogue reads 1 ds_read_b32)
    *(float4*)&S.p1.cn[t * 4] = *(const float4*)(cn + t * 4);

    // B chunk 0 global loads (issue early, store after A phase)
    uint4 st0[4];
    #pragma unroll
    for (int i = 0; i < 4; ++i) st0[i] = cbf8[(i << 8) + t];

    // A phase: wave w loads/converts its 16 positions (z scaled x16 -> fp8);
    // exact fp32 z^2 accumulated from the same loads.
    ull af[8];
    float z2 = 0.f;
    const float* zb = z + ((size_t)b << 18) + hw0;
    {
        const float* zp = zb + (w * 16 + col) + ((q * 8) << 10);
        #pragma unroll
        for (int ks = 0; ks < 8; ++ks) {
            const float* sp = zp + ((ks * 32) << 10);
            float v[8];
            #pragma unroll
            for (int j = 0; j < 8; ++j) v[j] = sp[j << 10];
            #pragma unroll
            for (int j = 0; j < 8; ++j) z2 += v[j] * v[j];
            int lo = 0, hi = 0;
            lo = __builtin_amdgcn_cvt_pk_fp8_f32(v[0]*16.f, v[1]*16.f, lo, false);
            lo = __builtin_amdgcn_cvt_pk_fp8_f32(v[2]*16.f, v[3]*16.f, lo, true);
            hi = __builtin_amdgcn_cvt_pk_fp8_f32(v[4]*16.f, v[5]*16.f, hi, false);
            hi = __builtin_amdgcn_cvt_pk_fp8_f32(v[6]*16.f, v[7]*16.f, hi, true);
            af[ks] = ((ull)(unsigned)hi << 32) | (unsigned)lo;
        }
    }

    // share A-frags (wave mi's af[ks] at lane L IS m-frag mi for every wave)
    #pragma unroll
    for (int ks = 0; ks < 8; ++ks) S.p1.A[w][ks][L] = af[ks];
    #pragma unroll
    for (int i = 0; i < 4; ++i) S.p1.B[0][(i << 8) + t] = st0[i];

    __syncthreads();

    // all 4 m-frags into registers (one-time, 2-way bank aliasing = free)
    ull am[4][8];
    #pragma unroll
    for (int mi = 0; mi < 4; ++mi)
        #pragma unroll
        for (int ks = 0; ks < 8; ++ks)
            am[mi][ks] = S.p1.A[mi][ks][L];

    float minv[4][4];
    #pragma unroll
    for (int mi = 0; mi < 4; ++mi)
        #pragma unroll
        for (int r = 0; r < 4; ++r) minv[mi][r] = 3.4e38f;

    const float SC = -4.8828125e-4f;   // -2 / (16*256)
    for (int it = 0; it < 16; ++it) {
        const int cur = it & 1;
        uint4 st2[4];
        if (it < 15) {
            #pragma unroll
            for (int i = 0; i < 4; ++i) st2[i] = cbf8[((it + 1) << 10) + (i << 8) + t];
        }
        // wave w reads only its nt-group's 8 frags (4 KB) from the chunk
        const ull* bb = (const ull*)&S.p1.B[cur][0];
        ull breg[8];
        #pragma unroll
        for (int ks = 0; ks < 8; ++ks)
            breg[ks] = bb[((w * 8 + ks) << 6) + L];

        f32x4 a0 = {0,0,0,0}, a1 = {0,0,0,0}, a2 = {0,0,0,0}, a3 = {0,0,0,0};
        #pragma unroll
        for (int ks = 0; ks < 8; ++ks) {        // 4 independent chains
            a0 = __builtin_amdgcn_mfma_f32_16x16x32_fp8_fp8((long long)am[0][ks], (long long)breg[ks], a0, 0, 0, 0);
            a1 = __builtin_amdgcn_mfma_f32_16x16x32_fp8_fp8((long long)am[1][ks], (long long)breg[ks], a1, 0, 0, 0);
            a2 = __builtin_amdgcn_mfma_f32_16x16x32_fp8_fp8((long long)am[2][ks], (long long)breg[ks], a2, 0, 0, 0);
            a3 = __builtin_amdgcn_mfma_f32_16x16x32_fp8_fp8((long long)am[3][ks], (long long)breg[ks], a3, 0, 0, 0);
        }

        const unsigned pn = (unsigned)(it * 4 + w);        // nt, 6 bits
        const float cnv = S.p1.cn[((it * 4 + w) << 4) + col];
        #pragma unroll
        for (int mi = 0; mi < 4; ++mi) {
            const f32x4& aa = (mi == 0) ? a0 : (mi == 1) ? a1 : (mi == 2) ? a2 : a3;
            #pragma unroll
            for (int r = 0; r < 4; ++r) {
                float d = fmaf(SC, aa[r], cnv);
                d = __uint_as_float((__float_as_uint(d) & ~63u) | pn);
                minv[mi][r] = fminf(minv[mi][r], d);
            }
        }
        if (it < 15) {
            #pragma unroll
            for (int i = 0; i < 4; ++i) S.p1.B[cur ^ 1][(i << 8) + t] = st2[i];
        }
        __syncthreads();
    }

    // within-wave min over the 16 code-cols; winners -> LDS (packed v kept)
    #pragma unroll
    for (int mi = 0; mi < 4; ++mi) {
        #pragma unroll
        for (int r = 0; r < 4; ++r) {
            float v = minv[mi][r];
            int cd = ((__float_as_int(v) & 63) << 4) | col;
            #pragma unroll
            for (int d = 1; d < 16; d <<= 1) {
                float ov = __shfl_xor(v, d, 64);
                int   oc = __shfl_xor(cd, d, 64);
                if (ov < v || (ov == v && oc < cd)) { v = ov; cd = oc; }
            }
            if (col == 0) {
                int p = mi * 16 + q * 4 + r;   // position 0..63
                Dw[w][p] = v;
                Cw[w][p] = cd;
            }
        }
    }
    __syncthreads();

    // cross-wave min (each wave held a disjoint quarter of the codes)
    float dpart = 0.f;
    if (w == 0) {
        float v = Dw[0][L]; int cd = Cw[0][L];
        #pragma unroll
        for (int ww = 1; ww < 4; ++ww) {
            float ov = Dw[ww][L]; int oc = Cw[ww][L];
            if (ov < v || (ov == v && oc < cd)) { v = ov; cd = oc; }
        }
        codeS[L] = cd;
        dpart = __uint_as_float(__float_as_uint(v) & ~63u);
    }

    float tot = z2 + dpart;
    #pragma unroll
    for (int off = 32; off; off >>= 1) tot += __shfl_down(tot, off, 64);
    if (L == 0) wsum[w] = tot;
    __syncthreads();
    if (t == 0)
        atomicAdd(loss, (wsum[0] + wsum[1] + wsum[2] + wsum[3]) * (1.25f / (float)NELEM));

    // Phase C/D: gather fp32 codebook rows (coalesced), transpose via LDS,
    // write out. Two 32-pos chunks so Q fits the union.
    const size_t obase = ((size_t)b << 18) + hw0;
    const int pg = L & 7, cidx = L >> 3;
    #pragma unroll
    for (int ch = 0; ch < 2; ++ch) {
        __syncthreads();
        #pragma unroll
        for (int rr = 0; rr < 8; ++rr) {
            int row = w * 8 + rr;
            int code = codeS[ch * 32 + row];
            float4 v = *(const float4*)(cb + ((size_t)code << 8) + (L << 2));
            float* qp = &S.Q[row][L << 2];
            qp[0] = v.x; qp[1] = v.y; qp[2] = v.z; qp[3] = v.w;
        }
        __syncthreads();
        #pragma unroll
        for (int i = 0; i < 8; ++i) {
            int c = w * 64 + i * 8 + cidx;
            int p0 = pg * 4;
            float4 qv;
            qv.x = S.Q[p0 + 0][c]; qv.y = S.Q[p0 + 1][c];
            qv.z = S.Q[p0 + 2][c]; qv.w = S.Q[p0 + 3][c];
            *(float4*)(out + obase + ((size_t)c << 10) + ch * 32 + p0) = qv;
        }
    }
}

// ---------------------------------------------------------------------------
extern "C" void kernel_launch(void* const* d_in, const int* in_sizes, int n_in,
                              void* d_out, int out_size, void* d_ws, size_t ws_size,
                              hipStream_t stream) {
    const float* z  = (const float*)d_in[0];
    const float* cb = (const float*)d_in[1];
    float* out  = (float*)d_out;
    float* cn   = (float*)d_ws;                              // 4 KB
    uint2* cbf8 = (uint2*)((char*)d_ws + 4096);              // 256 KB
    float* loss = out + NELEM;

    prep_kernel<<<128, 256, 0, stream>>>(cb, cbf8, cn, loss);
    vq_kernel<<<512, 256, 0, stream>>>(z, (const uint4*)cbf8, cb, cn, out, loss);
}